// Round 2
// baseline (240.439 us; speedup 1.0000x reference)
//
#include <hip/hip_runtime.h>
#include <math.h>

#define NROWS 65536
#define KCL   512
#define NDIM  128
#define CE_IDX ((size_t)NROWS * (size_t)KCL)
#define LN_2PI 1.83787706641f

using f32x4  = __attribute__((ext_vector_type(4))) float;
using short8 = __attribute__((ext_vector_type(8))) short;

__device__ __forceinline__ unsigned short f2bf(float f) {
    unsigned u = __float_as_uint(f);
    return (unsigned short)((u + 0x7fffu + ((u >> 16) & 1u)) >> 16);
}

// hardware packed f32->bf16 (RNE, same rounding as f2bf), 2 elems/instr
__device__ __forceinline__ unsigned cvt_pk_bf16(float lo, float hi) {
    unsigned r;
    asm("v_cvt_pk_bf16_f32 %0, %1, %2" : "=v"(r) : "v"(lo), "v"(hi));
    return r;
}

// ---------------------------------------------------------------------------
// Prep 1: W in frag-major layout (unchanged). Cluster n = t*16+m, column j in
// [0,256) (j<128: -2*c*dinv, j>=128: dinv). Fragment block c = j>>3, elem
// e = j&7. Linear short offset: t*4096 + c*128 + m*8 + e.
// ---------------------------------------------------------------------------
__global__ void k_prep(const float* __restrict__ centers,
                       const float* __restrict__ Dp,
                       unsigned short* __restrict__ W,
                       float* __restrict__ log_det,
                       float* __restrict__ cdotc) {
    int n = blockIdx.x;
    int d = threadIdx.x;
    int t = n >> 4, m = n & 15;
    float Dabs = fabsf(Dp[n * NDIM + d]) + 1e-8f;
    float dinv = 1.0f / Dabs;
    float c = centers[n * NDIM + d];
    int j1 = d, j2 = 128 + d;
    W[t * 4096 + (j1 >> 3) * 128 + m * 8 + (j1 & 7)] = f2bf(-2.0f * c * dinv);
    W[t * 4096 + (j2 >> 3) * 128 + m * 8 + (j2 & 7)] = f2bf(dinv);
    float lg = logf(Dabs);
    float cc = c * c * dinv;
    #pragma unroll
    for (int s = 32; s >= 1; s >>= 1) {
        lg += __shfl_xor(lg, s);
        cc += __shfl_xor(cc, s);
    }
    __shared__ float sred[4];
    if ((d & 63) == 0) { sred[(d >> 6) * 2 + 0] = lg; sred[(d >> 6) * 2 + 1] = cc; }
    __syncthreads();
    if (d == 0) { log_det[n] = sred[0] + sred[2]; cdotc[n] = sred[1] + sred[3]; }
}

// ---------------------------------------------------------------------------
// Prep 2: dss[k] = exp(dsf - max dsf), inv_sum = 1/sum(dss), zero ce slot.
// ---------------------------------------------------------------------------
__global__ void k_scale(const float* __restrict__ log_det,
                        float* __restrict__ dss,
                        float* __restrict__ inv_sum,
                        float* __restrict__ ce_slot) {
    int k = threadIdx.x;
    float dsf = -0.5f * log_det[k];
    float m = dsf;
    #pragma unroll
    for (int s = 32; s >= 1; s >>= 1) m = fmaxf(m, __shfl_xor(m, s));
    __shared__ float sm[KCL / 64], ss[KCL / 64];
    if ((k & 63) == 0) sm[k >> 6] = m;
    __syncthreads();
    float mm = sm[0];
    #pragma unroll
    for (int i = 1; i < KCL / 64; i++) mm = fmaxf(mm, sm[i]);
    float v = __expf(dsf - mm);
    dss[k] = v;
    float s = v;
    #pragma unroll
    for (int sh = 32; sh >= 1; sh >>= 1) s += __shfl_xor(s, sh);
    if ((k & 63) == 0) ss[k >> 6] = s;
    __syncthreads();
    if (k == 0) {
        float tot = 0.0f;
        #pragma unroll
        for (int i = 0; i < KCL / 64; i++) tot += ss[i];
        *inv_sum = 1.0f / tot;
        *ce_slot = 0.0f;
    }
}

// ---------------------------------------------------------------------------
// Main, barrier-free GEMM: 4 waves/block; wave w owns rows [blk*16,+16) x
// cluster quarter w (128 cols) -> acc[8] = 32 regs. W (256 KB, L2-resident)
// is streamed straight from global into VGPRs as 64 unrolled dwordx4 loads
// per wave (1 KB/instr coalesced) feeding MFMA directly -- no LDS staging,
// no main-loop __syncthreads, waves run free. Epilogue combines the 4
// col-quarters' (min, argmin-key/ds, sum) per row via 2 small LDS exchanges.
// argmin tracks (key, ds); payload = key - 1.5*ds (== ldc - 0.5*ds).
// ---------------------------------------------------------------------------
__global__ __launch_bounds__(256) __attribute__((amdgpu_waves_per_eu(3, 8)))
void k_main(const float* __restrict__ x,
            const unsigned short* __restrict__ W,
            const float* __restrict__ log_det,
            const float* __restrict__ cdotc,
            const float* __restrict__ dss,
            const float* __restrict__ inv_sum,
            float* __restrict__ out) {
    __shared__ float s_cd[KCL], s_ld[KCL], s_ds[KCL];
    __shared__ float ex_mn[4][16], ex_key[4][16], ex_ds[4][16], ex_sg[4][16];

    const int tid = threadIdx.x;
    s_cd[tid] = cdotc[tid];   s_cd[tid + 256] = cdotc[tid + 256];
    s_ld[tid] = log_det[tid]; s_ld[tid + 256] = log_det[tid + 256];
    s_ds[tid] = dss[tid];     s_ds[tid + 256] = dss[tid + 256];

    const int lane = tid & 63;
    const int w = __builtin_amdgcn_readfirstlane(tid >> 6);   // col quarter
    const int m = lane & 15;      // A row / B col within tile
    const int q = lane >> 4;      // quad; C rows = q*4+r
    const int r0 = blockIdx.x * 16;

    // ---- A fragments: lane(q,m) holds row r0+m, dims kk*32+q*8 .. +7 ----
    const float* xp = x + (size_t)(r0 + m) * NDIM + q * 8;
    short8 afx[4], afxx[4];
    #pragma unroll
    for (int kk = 0; kk < 4; kk++) {
        float4 a0 = *(const float4*)(xp + kk * 32);
        float4 a1 = *(const float4*)(xp + kk * 32 + 4);
        union { unsigned u[4]; short8 s; } A, AX;
        A.u[0]  = cvt_pk_bf16(a0.x, a0.y);
        A.u[1]  = cvt_pk_bf16(a0.z, a0.w);
        A.u[2]  = cvt_pk_bf16(a1.x, a1.y);
        A.u[3]  = cvt_pk_bf16(a1.z, a1.w);
        AX.u[0] = cvt_pk_bf16(a0.x * a0.x, a0.y * a0.y);
        AX.u[1] = cvt_pk_bf16(a0.z * a0.z, a0.w * a0.w);
        AX.u[2] = cvt_pk_bf16(a1.x * a1.x, a1.y * a1.y);
        AX.u[3] = cvt_pk_bf16(a1.z * a1.z, a1.w * a1.w);
        afx[kk] = A.s; afxx[kk] = AX.s;
    }

    f32x4 acc[8];
    #pragma unroll
    for (int v = 0; v < 8; v++) acc[v] = (f32x4){0.f, 0.f, 0.f, 0.f};

    // ---- GEMM: wave's 8 tiles (64 KB) direct from L2, compiler-pipelined ----
    const unsigned short* gWq = W + ((size_t)w * 8) * 4096 + lane * 8;
    #pragma unroll
    for (int v = 0; v < 8; v++) {
        const unsigned short* tb = gWq + v * 4096;
        #pragma unroll
        for (int kk = 0; kk < 4; kk++) {
            short8 b0 = *(const short8*)(tb + kk * 512);
            short8 b1 = *(const short8*)(tb + 2048 + kk * 512);
            acc[v] = __builtin_amdgcn_mfma_f32_16x16x32_bf16(afx[kk],  b0, acc[v], 0, 0, 0);
            acc[v] = __builtin_amdgcn_mfma_f32_16x16x32_bf16(afxx[kk], b1, acc[v], 0, 0, 0);
        }
    }

    __syncthreads();   // consts staged at top are now visible to all waves

    // ---- E1: ds = acc + cdotc; quarter-local min(ds), argmin(ds+log_det) ----
    const int colbase = w * 128 + m;
    float mn[4], bkey[4], bds[4];
    #pragma unroll
    for (int r = 0; r < 4; r++) { mn[r] = INFINITY; bkey[r] = INFINITY; bds[r] = 0.f; }
    #pragma unroll
    for (int v = 0; v < 8; v++) {
        const int col = colbase + v * 16;
        float cd = s_cd[col], ldc = s_ld[col];
        #pragma unroll
        for (int r = 0; r < 4; r++) {
            float ds = acc[v][r] + cd;
            acc[v][r] = ds;
            mn[r] = fminf(mn[r], ds);
            float key = ds + ldc;
            bool t = key < bkey[r];
            bkey[r] = t ? key : bkey[r];
            bds[r]  = t ? ds  : bds[r];
        }
    }
    #pragma unroll
    for (int s = 1; s < 16; s <<= 1) {
        #pragma unroll
        for (int r = 0; r < 4; r++) {
            mn[r] = fminf(mn[r], __shfl_xor(mn[r], s));
            float ok = __shfl_xor(bkey[r], s);
            float od = __shfl_xor(bds[r],  s);
            bool t = ok < bkey[r];
            bkey[r] = t ? ok : bkey[r];
            bds[r]  = t ? od : bds[r];
        }
    }
    if (m == 0) {
        #pragma unroll
        for (int r = 0; r < 4; r++) {
            ex_mn[w][q * 4 + r]  = mn[r];
            ex_key[w][q * 4 + r] = bkey[r];
            ex_ds[w][q * 4 + r]  = bds[r];
        }
    }
    __syncthreads();

    // ---- cross-quarter combine: global min + argmin payload ----
    float hmn[4], pay[4], Sg[4];
    #pragma unroll
    for (int r = 0; r < 4; r++) {
        const int row = q * 4 + r;
        float g0 = fminf(ex_mn[0][row], ex_mn[1][row]);
        float g1 = fminf(ex_mn[2][row], ex_mn[3][row]);
        hmn[r] = 0.5f * fminf(g0, g1);
        float bk = ex_key[0][row], bd = ex_ds[0][row];
        #pragma unroll
        for (int w2 = 1; w2 < 4; w2++) {
            float ok = ex_key[w2][row], od = ex_ds[w2][row];
            bool t = ok < bk;
            bk = t ? ok : bk;
            bd = t ? od : bd;
        }
        pay[r] = fmaf(-1.5f, bd, bk);   // = ldc - 0.5*ds at the argmin
        Sg[r] = 0.f;
    }

    // ---- E2: gmm numerators + quarter-sum (stash ng back into acc) ----
    float dsv[8];
    #pragma unroll
    for (int v = 0; v < 8; v++) {
        dsv[v] = s_ds[colbase + v * 16];
        #pragma unroll
        for (int r = 0; r < 4; r++) {
            float ng = dsv[v] * __expf(fmaf(-0.5f, acc[v][r], hmn[r]));
            Sg[r] += ng;
            acc[v][r] = ng;
        }
    }
    #pragma unroll
    for (int s = 1; s < 16; s <<= 1)
        #pragma unroll
        for (int r = 0; r < 4; r++) Sg[r] += __shfl_xor(Sg[r], s);

    if (m == 0) {
        #pragma unroll
        for (int r = 0; r < 4; r++) ex_sg[w][q * 4 + r] = Sg[r];
    }
    __syncthreads();

    const float isum05 = 0.5f * (*inv_sum);
    float iSg05[4];
    #pragma unroll
    for (int r = 0; r < 4; r++) {
        const int row = q * 4 + r;
        float st = (ex_sg[0][row] + ex_sg[1][row]) + (ex_sg[2][row] + ex_sg[3][row]);
        iSg05[r] = 0.5f / st;
    }

    // ---- E3: out = log(max(ng*iSg05, 5e-9) + dss*isum05), coalesced ----
    #pragma unroll
    for (int v = 0; v < 8; v++) {
        float bt = dsv[v] * isum05;
        #pragma unroll
        for (int r = 0; r < 4; r++) {
            float z = fmaxf(acc[v][r] * iSg05[r], 5e-9f) + bt;
            out[(size_t)(r0 + q * 4 + r) * KCL + colbase + v * 16] = __logf(z);
        }
    }

    // ---- ce: wave 0 carries the (already globally-combined) payload ----
    if (w == 0) {
        float ce = (pay[0] + pay[1]) + (pay[2] + pay[3]);
        if (m != 0) ce = 0.0f;
        ce += __shfl_xor(ce, 16);
        ce += __shfl_xor(ce, 32);
        if (lane == 0) {
            float vv = (-1.0f / (float)NROWS) *
                       (ce + 16.0f * (-0.5f * (float)NDIM * LN_2PI));
            atomicAdd(out + CE_IDX, vv);
        }
    }
}

extern "C" void kernel_launch(void* const* d_in, const int* in_sizes, int n_in,
                              void* d_out, int out_size, void* d_ws, size_t ws_size,
                              hipStream_t stream) {
    const float* x       = (const float*)d_in[0];
    const float* centers = (const float*)d_in[1];
    const float* Dp      = (const float*)d_in[2];
    float* out = (float*)d_out;

    unsigned short* W = (unsigned short*)d_ws;
    float* log_det = (float*)((char*)d_ws + (size_t)KCL * 256 * sizeof(unsigned short));
    float* cdotc   = log_det + KCL;
    float* dss     = cdotc + KCL;
    float* inv_sum = dss + KCL;

    k_prep<<<KCL, NDIM, 0, stream>>>(centers, Dp, W, log_det, cdotc);
    k_scale<<<1, KCL, 0, stream>>>(log_det, dss, inv_sum, out + CE_IDX);
    k_main<<<NROWS / 16, 256, 0, stream>>>(x, W, log_det, cdotc, dss, inv_sum, out);
}

// Round 3
// 194.692 us; speedup vs baseline: 1.2350x; 1.2350x over previous
//
#include <hip/hip_runtime.h>
#include <math.h>

#define NROWS 65536
#define KCL   512
#define NDIM  128
#define CE_IDX ((size_t)NROWS * (size_t)KCL)
#define LN_2PI 1.83787706641f

using f32x4  = __attribute__((ext_vector_type(4))) float;
using short8 = __attribute__((ext_vector_type(8))) short;

__device__ __forceinline__ unsigned short f2bf(float f) {
    unsigned u = __float_as_uint(f);
    return (unsigned short)((u + 0x7fffu + ((u >> 16) & 1u)) >> 16);
}

// hardware packed f32->bf16 (RNE, same rounding as f2bf), 2 elems/instr
__device__ __forceinline__ unsigned cvt_pk_bf16(float lo, float hi) {
    unsigned r;
    asm("v_cvt_pk_bf16_f32 %0, %1, %2" : "=v"(r) : "v"(lo), "v"(hi));
    return r;
}

// async global->LDS, 16 B per lane; LDS dest = wave-uniform base + lane*16
__device__ __forceinline__ void gld_lds16(const void* g, void* l) {
    __builtin_amdgcn_global_load_lds(
        (const __attribute__((address_space(1))) unsigned int*)g,
        (__attribute__((address_space(3))) unsigned int*)l,
        16, 0, 0);
}

// ---------------------------------------------------------------------------
// Prep: W in frag-major layout (unchanged). Cluster n = t*16+m, column j in
// [0,256) (j<128: -2*c*dinv, j>=128: dinv). Fragment block c = j>>3, elem
// e = j&7. Linear short offset: t*4096 + c*128 + m*8 + e.
// dss/inv_sum no longer precomputed: |log_det| <= ~13.5 so exp(-0.5*log_det)
// is f32-safe without the max-shift (softmax is shift-invariant) -> k_main
// computes them in-block; k_scale kernel deleted.
// ---------------------------------------------------------------------------
__global__ void k_prep(const float* __restrict__ centers,
                       const float* __restrict__ Dp,
                       unsigned short* __restrict__ W,
                       float* __restrict__ log_det,
                       float* __restrict__ cdotc) {
    int n = blockIdx.x;
    int d = threadIdx.x;
    int t = n >> 4, m = n & 15;
    float Dabs = fabsf(Dp[n * NDIM + d]) + 1e-8f;
    float dinv = 1.0f / Dabs;
    float c = centers[n * NDIM + d];
    int j1 = d, j2 = 128 + d;
    W[t * 4096 + (j1 >> 3) * 128 + m * 8 + (j1 & 7)] = f2bf(-2.0f * c * dinv);
    W[t * 4096 + (j2 >> 3) * 128 + m * 8 + (j2 & 7)] = f2bf(dinv);
    float lg = logf(Dabs);
    float cc = c * c * dinv;
    #pragma unroll
    for (int s = 32; s >= 1; s >>= 1) {
        lg += __shfl_xor(lg, s);
        cc += __shfl_xor(cc, s);
    }
    __shared__ float sred[4];
    if ((d & 63) == 0) { sred[(d >> 6) * 2 + 0] = lg; sred[(d >> 6) * 2 + 1] = cc; }
    __syncthreads();
    if (d == 0) { log_det[n] = sred[0] + sred[2]; cdotc[n] = sred[1] + sred[3]; }
}

// ---------------------------------------------------------------------------
// Main: 64 rows/block, 8 waves (512 thr). Wave (g = w>>1, h = w&1) owns rows
// [blk*64 + g*16, +16) x col-half h (256 cols) -> acc[16] = 64 regs.
// W (256 KB) streamed through LDS in 16 rounds x 16 KB (tiles {u, 16+u}),
// TRIPLE-buffered, prefetch distance 1, ONE raw s_barrier per round with
// counted s_waitcnt vmcnt(2) -- the next round's loads stay in flight across
// the barrier (no vmcnt(0) drain in the main loop). 8 waves share each staged
// tile; each wave stages 2 KB (2x gld_lds16). Blocks = 1024 -> W L2 traffic
// 256 MB (was 1 GB). waves_per_eu(4,8): live set ~116 regs -> 4 waves/SIMD.
// Epilogue: intra-wave 16-lane reduce + cross-half LDS combine; 1 atomic/blk.
// ---------------------------------------------------------------------------
__global__ __launch_bounds__(512) __attribute__((amdgpu_waves_per_eu(4, 8)))
void k_main(const float* __restrict__ x,
            const unsigned short* __restrict__ W,
            const float* __restrict__ log_det,
            const float* __restrict__ cdotc,
            float* __restrict__ out) {
    __shared__ __align__(16) short ldsW[3][8192];     // 3 x 16 KB round bufs
    __shared__ float s_cd[KCL], s_ld[KCL], s_ds[KCL];
    __shared__ float ex_mn[2][64], ex_key[2][64], ex_ds[2][64], ex_sg[2][64];
    __shared__ float sred[8], ce_part[4];
    __shared__ float s_invsum;

    const int tid = threadIdx.x;
    // ---- consts: stage cd/ld, derive dss = exp(-0.5*ld) and its sum ----
    {
        float ldv = log_det[tid];
        float cdv = cdotc[tid];
        s_ld[tid] = ldv;
        s_cd[tid] = cdv;
        float e = __expf(-0.5f * ldv);
        s_ds[tid] = e;
        float s = e;
        #pragma unroll
        for (int sh = 32; sh >= 1; sh >>= 1) s += __shfl_xor(s, sh);
        if ((tid & 63) == 0) sred[tid >> 6] = s;
    }

    const int lane = tid & 63;
    const int w = __builtin_amdgcn_readfirstlane(tid >> 6);
    const int g = w >> 1;         // row group: rows r0 + g*16 .. +15
    const int h = w & 1;          // col half: cols h*256 .. +255
    const int m = lane & 15;      // A row / B col within tile
    const int q = lane >> 4;      // quad; C rows = q*4+r
    const int r0 = blockIdx.x * 64;

    // ---- A fragments: lane(q,m) holds row r0+g*16+m, dims kk*32+q*8.. ----
    const float* xp = x + (size_t)(r0 + g * 16 + m) * NDIM + q * 8;
    short8 afx[4], afxx[4];
    #pragma unroll
    for (int kk = 0; kk < 4; kk++) {
        float4 a0 = *(const float4*)(xp + kk * 32);
        float4 a1 = *(const float4*)(xp + kk * 32 + 4);
        union { unsigned u[4]; short8 s; } A, AX;
        A.u[0]  = cvt_pk_bf16(a0.x, a0.y);
        A.u[1]  = cvt_pk_bf16(a0.z, a0.w);
        A.u[2]  = cvt_pk_bf16(a1.x, a1.y);
        A.u[3]  = cvt_pk_bf16(a1.z, a1.w);
        AX.u[0] = cvt_pk_bf16(a0.x * a0.x, a0.y * a0.y);
        AX.u[1] = cvt_pk_bf16(a0.z * a0.z, a0.w * a0.w);
        AX.u[2] = cvt_pk_bf16(a1.x * a1.x, a1.y * a1.y);
        AX.u[3] = cvt_pk_bf16(a1.z * a1.z, a1.w * a1.w);
        afx[kk] = A.s; afxx[kk] = AX.s;
    }

    f32x4 acc[16];
    #pragma unroll
    for (int t = 0; t < 16; t++) acc[t] = (f32x4){0.f, 0.f, 0.f, 0.f};

    // staging: round u = 16 KB (tile u -> LDS[0..8K), tile 16+u -> [8K..16K)).
    // wave w stages bytes [w*2048, +2048): w<4 from tile u, w>=4 from 16+u.
    const char* gWb = (const char*)W + ((w & 4) ? 16 * 8192 : 0)
                      + (w & 3) * 2048 + (size_t)lane * 16;
    char* lWb = (char*)&ldsW[0][0] + w * 2048;

    // prologue: stage round 0 -> buf 0; one full drain (also consts barrier)
    gld_lds16(gWb, lWb);
    gld_lds16(gWb + 1024, lWb + 1024);
    __syncthreads();

    if (tid == 0) {
        float tot = 0.0f;
        #pragma unroll
        for (int i = 0; i < 8; i++) tot += sred[i];
        s_invsum = 1.0f / tot;
    }

    #pragma unroll
    for (int u = 0; u < 16; ++u) {
        if (u < 15) {
            const char* s = gWb + (size_t)(u + 1) * 8192;
            char* l = (char*)&ldsW[0][0] + ((u + 1) % 3) * 16384 + w * 2048;
            gld_lds16(s, l);
            gld_lds16(s + 1024, l + 1024);
            // wait for round-u loads (issued last round); the 2 just-issued fly on
            asm volatile("s_waitcnt vmcnt(2)" ::: "memory");
        } else {
            asm volatile("s_waitcnt vmcnt(0)" ::: "memory");
        }
        __builtin_amdgcn_s_barrier();
        asm volatile("" ::: "memory");
        const short* lb = &ldsW[u % 3][h * 4096];
        #pragma unroll
        for (int kk = 0; kk < 4; kk++) {
            short8 b0 = *(const short8*)(lb + kk * 512 + lane * 8);
            short8 b1 = *(const short8*)(lb + 2048 + kk * 512 + lane * 8);
            acc[u] = __builtin_amdgcn_mfma_f32_16x16x32_bf16(afx[kk],  b0, acc[u], 0, 0, 0);
            acc[u] = __builtin_amdgcn_mfma_f32_16x16x32_bf16(afxx[kk], b1, acc[u], 0, 0, 0);
        }
    }

    // ---- E1: ds = acc + cdotc; half-local min(ds), argmin(ds + log_det) ----
    const int colbase = h * 256 + m;
    float mn[4], bkey[4], bds[4];
    #pragma unroll
    for (int r = 0; r < 4; r++) { mn[r] = INFINITY; bkey[r] = INFINITY; bds[r] = 0.f; }
    #pragma unroll
    for (int u = 0; u < 16; u++) {
        const int col = colbase + u * 16;
        float cd = s_cd[col], ldc = s_ld[col];
        #pragma unroll
        for (int r = 0; r < 4; r++) {
            float ds = acc[u][r] + cd;
            acc[u][r] = ds;
            mn[r] = fminf(mn[r], ds);
            float key = ds + ldc;
            bool t = key < bkey[r];
            bkey[r] = t ? key : bkey[r];
            bds[r]  = t ? ds  : bds[r];
        }
    }
    #pragma unroll
    for (int s = 1; s < 16; s <<= 1) {
        #pragma unroll
        for (int r = 0; r < 4; r++) {
            mn[r] = fminf(mn[r], __shfl_xor(mn[r], s));
            float ok = __shfl_xor(bkey[r], s);
            float od = __shfl_xor(bds[r],  s);
            bool t = ok < bkey[r];
            bkey[r] = t ? ok : bkey[r];
            bds[r]  = t ? od : bds[r];
        }
    }
    const int rowb = g * 16 + q * 4;   // + r: block-row in [0,64)
    if (m == 0) {
        #pragma unroll
        for (int r = 0; r < 4; r++) {
            ex_mn[h][rowb + r]  = mn[r];
            ex_key[h][rowb + r] = bkey[r];
            ex_ds[h][rowb + r]  = bds[r];
        }
    }
    __syncthreads();

    // ---- cross-half combine (h=0 holds cols 0..255: first-index on ties) ----
    float hmn[4], pay[4], Sg[4];
    #pragma unroll
    for (int r = 0; r < 4; r++) {
        mn[r] = fminf(mn[r], ex_mn[h ^ 1][rowb + r]);
        float ok = ex_key[h ^ 1][rowb + r];
        float od = ex_ds[h ^ 1][rowb + r];
        bool t = h ? (ok <= bkey[r]) : (ok < bkey[r]);
        float bk = t ? ok : bkey[r];
        float bd = t ? od : bds[r];
        pay[r] = fmaf(-1.5f, bd, bk);   // = ldc - 0.5*ds at the argmin
        hmn[r] = 0.5f * mn[r];
        Sg[r] = 0.f;
    }

    // ---- E2: gmm numerators + half-sum (stash ng back into acc) ----
    #pragma unroll
    for (int u = 0; u < 16; u++) {
        float dsc = s_ds[colbase + u * 16];
        #pragma unroll
        for (int r = 0; r < 4; r++) {
            float ng = dsc * __expf(fmaf(-0.5f, acc[u][r], hmn[r]));
            Sg[r] += ng;
            acc[u][r] = ng;
        }
    }
    #pragma unroll
    for (int s = 1; s < 16; s <<= 1)
        #pragma unroll
        for (int r = 0; r < 4; r++) Sg[r] += __shfl_xor(Sg[r], s);

    if (m == 0) {
        #pragma unroll
        for (int r = 0; r < 4; r++) ex_sg[h][rowb + r] = Sg[r];
    }
    // ce partial: h==0 waves, payload already globally combined
    if (h == 0) {
        float ce = (pay[0] + pay[1]) + (pay[2] + pay[3]);
        if (m != 0) ce = 0.0f;
        ce += __shfl_xor(ce, 16);
        ce += __shfl_xor(ce, 32);
        if (lane == 0) ce_part[g] = ce;
    }
    __syncthreads();

    if (tid == 0) {
        float ce = (ce_part[0] + ce_part[1]) + (ce_part[2] + ce_part[3]);
        float v = (-1.0f / (float)NROWS) *
                  (ce + 64.0f * (-0.5f * (float)NDIM * LN_2PI));
        atomicAdd(out + CE_IDX, v);
    }

    float iSg05[4];
    #pragma unroll
    for (int r = 0; r < 4; r++)
        iSg05[r] = 0.5f / (Sg[r] + ex_sg[h ^ 1][rowb + r]);

    // ---- E3: out = log(max(ng*iSg05, 5e-9) + dss*isum05), coalesced ----
    const float isum05 = 0.5f * s_invsum;
    #pragma unroll
    for (int u = 0; u < 16; u++) {
        float bt = s_ds[colbase + u * 16] * isum05;
        #pragma unroll
        for (int r = 0; r < 4; r++) {
            float z = fmaxf(acc[u][r] * iSg05[r], 5e-9f) + bt;
            out[(size_t)(r0 + g * 16 + q * 4 + r) * KCL + colbase + u * 16] = __logf(z);
        }
    }
}

extern "C" void kernel_launch(void* const* d_in, const int* in_sizes, int n_in,
                              void* d_out, int out_size, void* d_ws, size_t ws_size,
                              hipStream_t stream) {
    const float* x       = (const float*)d_in[0];
    const float* centers = (const float*)d_in[1];
    const float* Dp      = (const float*)d_in[2];
    float* out = (float*)d_out;

    unsigned short* W = (unsigned short*)d_ws;
    float* log_det = (float*)((char*)d_ws + (size_t)KCL * 256 * sizeof(unsigned short));
    float* cdotc   = log_det + KCL;

    k_prep<<<KCL, NDIM, 0, stream>>>(centers, Dp, W, log_det, cdotc);
    hipMemsetAsync(out + CE_IDX, 0, sizeof(float), stream);
    k_main<<<NROWS / 64, 512, 0, stream>>>(x, W, log_det, cdotc, out);
}